// Round 2
// baseline (3619.841 us; speedup 1.0000x reference)
//
#include <hip/hip_runtime.h>
#include <hip/hip_bf16.h>

typedef __hip_bfloat16 bf16;

// flag: 1 = float tensors are bf16, 0 = float tensors are fp32
__device__ __forceinline__ float ldw(const void* p, long i, int isbf) {
    return isbf ? __bfloat162float(((const bf16*)p)[i]) : ((const float*)p)[i];
}

// ---------------------------------------------------------------- dtype detect
// Scan n 16-bit halves of a weight tensor. If underlying fp32, ~half the halves
// are random mantissa bits -> wild exponents. If bf16, all are sane weights.
__global__ void k_detect(const unsigned short* __restrict__ w, int n, int* __restrict__ flag) {
    __shared__ int cnt;
    if (threadIdx.x == 0) cnt = 0;
    __syncthreads();
    int bad = 0;
    for (int i = threadIdx.x; i < n; i += 256) {
        int e = (w[i] >> 7) & 0xFF;
        if (e == 0xFF || (e != 0 && (e < 64 || e > 190))) bad++;
    }
    atomicAdd(&cnt, bad);
    __syncthreads();
    if (threadIdx.x == 0) *flag = (cnt > n / 16) ? 0 : 1;
}

// ---------------------------------------------------------------- utilities
__global__ void k_cvt_in(const void* __restrict__ s, float* __restrict__ d, int n,
                         const int* __restrict__ flag) {
    int i = blockIdx.x * 256 + threadIdx.x;
    if (i < n) d[i] = ldw(s, i, *flag);
}
__global__ void k_out(const float* __restrict__ s, void* __restrict__ d, int n,
                      const int* __restrict__ flag) {
    int i = blockIdx.x * 256 + threadIdx.x;
    if (i < n) {
        if (*flag) ((bf16*)d)[i] = __float2bfloat16(s[i]);
        else       ((float*)d)[i] = s[i];
    }
}
__global__ void k_zero(float* __restrict__ d, int n) {
    int i = blockIdx.x * 256 + threadIdx.x;
    if (i < n) d[i] = 0.f;
}
__global__ void k_deg(const int* __restrict__ dst, float* __restrict__ deg, int E) {
    int i = blockIdx.x * 256 + threadIdx.x;
    if (i < E) atomicAdd(&deg[dst[i]], 1.0f);
}
__global__ void k_dinv(const float* __restrict__ deg, float* __restrict__ dinv, int n) {
    int i = blockIdx.x * 256 + threadIdx.x;
    if (i < n) dinv[i] = rsqrtf(fmaxf(deg[i] + 1.0f, 1.0f));  // +1 self loop
}

// ---------------------------------------------------------------- matmul
// C(MxN) = A(MxK,f32) @ W(KxN,flagged dtype, element offset woff) [+bias][+radd][relu]
__global__ __launch_bounds__(256) void k_mm(
    const float* __restrict__ A, const void* __restrict__ Wt,
    const void* __restrict__ bias, const float* __restrict__ radd,
    float* __restrict__ C, int M, int K, int N, long woff, int relu,
    const int* __restrict__ flag)
{
    __shared__ float As[16][64];
    __shared__ float Bs[16][64];
    const int isbf = *flag;
    const int tid = threadIdx.x;
    const int tx = tid & 15, ty = tid >> 4;
    const int bx = blockIdx.x, by = blockIdx.y;
    float acc[4][4] = {};
    const int amm = tid >> 2, akb = (tid & 3) << 2;
    const int bkk = tid >> 4, bnb = (tid & 15) << 2;
    for (int k0 = 0; k0 < K; k0 += 16) {
        int arow = by * 64 + amm;
        #pragma unroll
        for (int u = 0; u < 4; u++) {
            int kk = akb + u, kg = k0 + kk;
            float v = 0.f;
            if (arow < M && kg < K) v = A[(long)arow * K + kg];
            As[kk][amm] = v;
        }
        {
            int kg = k0 + bkk;
            #pragma unroll
            for (int u = 0; u < 4; u++) {
                int col = bx * 64 + bnb + u;
                float v = 0.f;
                if (kg < K && col < N) v = ldw(Wt, woff + (long)kg * N + col, isbf);
                Bs[bkk][bnb + u] = v;
            }
        }
        __syncthreads();
        #pragma unroll
        for (int kk = 0; kk < 16; kk++) {
            float a[4], b[4];
            #pragma unroll
            for (int i = 0; i < 4; i++) a[i] = As[kk][ty + i * 16];
            #pragma unroll
            for (int j = 0; j < 4; j++) b[j] = Bs[kk][tx + j * 16];
            #pragma unroll
            for (int i = 0; i < 4; i++)
                #pragma unroll
                for (int j = 0; j < 4; j++)
                    acc[i][j] = fmaf(a[i], b[j], acc[i][j]);
        }
        __syncthreads();
    }
    #pragma unroll
    for (int i = 0; i < 4; i++) {
        int r = by * 64 + ty + i * 16;
        if (r >= M) continue;
        #pragma unroll
        for (int j = 0; j < 4; j++) {
            int c = bx * 64 + tx + j * 16;
            if (c >= N) continue;
            float v = acc[i][j];
            if (bias) v += ldw(bias, c, isbf);
            if (radd) v += radd[c];
            if (relu) v = fmaxf(v, 0.f);
            C[(long)r * N + c] = v;
        }
    }
}

// rowvec[n] = sum_c gmax[c] * W[c*2048...] for FP2 rank-1 gmax contribution (N fixed 1024, K 2048)
__global__ void k_rowvec(const float* __restrict__ gmax, const void* __restrict__ W,
                         float* __restrict__ out, const int* __restrict__ flag) {
    int n = blockIdx.x * 256 + threadIdx.x;
    if (n >= 1024) return;
    const int isbf = *flag;
    float s = 0.f;
    for (int c = 0; c < 2048; c++) s += gmax[c] * ldw(W, (long)c * 1024 + n, isbf);
    out[n] = s;
}

// ---------------------------------------------------------------- GCN aggregation
__global__ void k_self(const float* __restrict__ t, const float* __restrict__ dinv,
                       float* __restrict__ out, int n, int C) {
    long i = blockIdx.x * 256L + threadIdx.x;
    if (i < (long)n * C) {
        int r = (int)(i / C);
        float d = dinv[r];
        out[i] = t[i] * d * d;
    }
}
__global__ void k_scatter(const float* __restrict__ t, const int* __restrict__ src,
                          const int* __restrict__ dst, const float* __restrict__ dinv,
                          float* __restrict__ out, int E, int C) {
    long i = blockIdx.x * 256L + threadIdx.x;
    if (i < (long)E * C) {
        int e = (int)(i / C);
        int c = (int)(i - (long)e * C);
        int s = src[e], d = dst[e];
        float coef = dinv[s] * dinv[d];
        atomicAdd(&out[(long)d * C + c], t[(long)s * C + c] * coef);
    }
}
__global__ void k_bias_relu(float* __restrict__ h, const void* __restrict__ b, int n, int C,
                            const int* __restrict__ flag) {
    long i = blockIdx.x * 256L + threadIdx.x;
    if (i < (long)n * C) {
        int c = (int)(i % C);
        h[i] = fmaxf(h[i] + ldw(b, c, *flag), 0.f);
    }
}

// ---------------------------------------------------------------- batchnorm (train) + relu, in place (n<=1024)
__global__ __launch_bounds__(256) void k_bn(float* __restrict__ h, const void* __restrict__ gamma,
                                            const void* __restrict__ beta, int n, int C,
                                            const int* __restrict__ flag) {
    int c = blockIdx.x;
    int tid = threadIdx.x;
    __shared__ float sm[256];
    float v[4];
    float s = 0.f;
    #pragma unroll
    for (int u = 0; u < 4; u++) {
        int r = tid + u * 256;
        v[u] = (r < n) ? h[(long)r * C + c] : 0.f;
        s += v[u];
    }
    sm[tid] = s; __syncthreads();
    for (int o = 128; o > 0; o >>= 1) { if (tid < o) sm[tid] += sm[tid + o]; __syncthreads(); }
    float mu = sm[0] / n;
    __syncthreads();
    float s2 = 0.f;
    #pragma unroll
    for (int u = 0; u < 4; u++) {
        int r = tid + u * 256;
        if (r < n) { float d = v[u] - mu; s2 += d * d; }
    }
    sm[tid] = s2; __syncthreads();
    for (int o = 128; o > 0; o >>= 1) { if (tid < o) sm[tid] += sm[tid + o]; __syncthreads(); }
    float var = sm[0] / n;
    float rs = rsqrtf(var + 1e-5f);
    float g = ldw(gamma, c, *flag), be = ldw(beta, c, *flag);
    #pragma unroll
    for (int u = 0; u < 4; u++) {
        int r = tid + u * 256;
        if (r < n) h[(long)r * C + c] = fmaxf((v[u] - mu) * rs * g + be, 0.f);
    }
}

__global__ __launch_bounds__(256) void k_colmax(const float* __restrict__ h, float* __restrict__ out,
                                                int n, int C) {
    int c = blockIdx.x;
    int tid = threadIdx.x;
    __shared__ float sm[256];
    float m = -3.0e38f;
    for (int r = tid; r < n; r += 256) m = fmaxf(m, h[(long)r * C + c]);
    sm[tid] = m; __syncthreads();
    for (int o = 128; o > 0; o >>= 1) { if (tid < o) sm[tid] = fmaxf(sm[tid], sm[tid + o]); __syncthreads(); }
    if (tid == 0) out[c] = sm[0];
}

// ---------------------------------------------------------------- gather / strided copy
__global__ void k_gather(const float* __restrict__ src, const int* __restrict__ idx,
                         float* __restrict__ dst, int n, int ncol, int ss, int ds, int doff) {
    long i = blockIdx.x * 256L + threadIdx.x;
    if (i < (long)n * ncol) {
        int r = (int)(i / ncol), c = (int)(i % ncol);
        dst[(long)r * ds + doff + c] = src[(long)idx[r] * ss + c];
    }
}
__global__ void k_copy(const float* __restrict__ src, float* __restrict__ dst,
                       int n, int ncol, int ss, int ds, int doff) {
    long i = blockIdx.x * 256L + threadIdx.x;
    if (i < (long)n * ncol) {
        int r = (int)(i / ncol), c = (int)(i % ncol);
        dst[(long)r * ds + doff + c] = src[(long)r * ss + c];
    }
}

// ---------------------------------------------------------------- kNN (k=3)
__global__ __launch_bounds__(256) void k_knn_find(const float* __restrict__ pdst,
                                                  const float* __restrict__ psrc,
                                                  int M, int Ns,
                                                  int* __restrict__ kidx, float* __restrict__ kw) {
    extern __shared__ float sp[];
    for (int i = threadIdx.x; i < Ns * 3; i += 256) sp[i] = psrc[i];
    __syncthreads();
    int d = blockIdx.x * 256 + threadIdx.x;
    if (d >= M) return;
    float x = pdst[d * 3], y = pdst[d * 3 + 1], z = pdst[d * 3 + 2];
    float nd = x * x + y * y + z * z;
    float bd0 = 3.4e38f, bd1 = 3.4e38f, bd2 = 3.4e38f;
    int bi0 = 0, bi1 = 0, bi2 = 0;
    for (int s = 0; s < Ns; s++) {
        float sx = sp[3 * s], sy = sp[3 * s + 1], sz = sp[3 * s + 2];
        float ns = sx * sx + sy * sy + sz * sz;
        float dot = x * sx + y * sy + z * sz;
        float d2 = nd + ns - 2.0f * dot;
        if (d2 < bd2) {
            if (d2 < bd0)      { bd2 = bd1; bi2 = bi1; bd1 = bd0; bi1 = bi0; bd0 = d2; bi0 = s; }
            else if (d2 < bd1) { bd2 = bd1; bi2 = bi1; bd1 = d2; bi1 = s; }
            else               { bd2 = d2; bi2 = s; }
        }
    }
    kidx[d * 3] = bi0; kidx[d * 3 + 1] = bi1; kidx[d * 3 + 2] = bi2;
    kw[d * 3]     = 1.0f / fmaxf(bd0, 1e-16f);
    kw[d * 3 + 1] = 1.0f / fmaxf(bd1, 1e-16f);
    kw[d * 3 + 2] = 1.0f / fmaxf(bd2, 1e-16f);
}

__global__ void k_knn_apply(const float* __restrict__ h, const int* __restrict__ kidx,
                            const float* __restrict__ kw, float* __restrict__ out,
                            int M, int C, int ds) {
    long i = blockIdx.x * 256L + threadIdx.x;
    if (i >= (long)M * C) return;
    int r = (int)(i / C), c = (int)(i % C);
    int i0 = kidx[r * 3], i1 = kidx[r * 3 + 1], i2 = kidx[r * 3 + 2];
    float w0 = kw[r * 3], w1 = kw[r * 3 + 1], w2 = kw[r * 3 + 2];
    float v = w0 * h[(long)i0 * C + c] + w1 * h[(long)i1 * C + c] + w2 * h[(long)i2 * C + c];
    out[(long)r * ds + c] = v / (w0 + w1 + w2);
}

// ---------------------------------------------------------------- launch
extern "C" void kernel_launch(void* const* d_in, const int* in_sizes, int n_in,
                              void* d_out, int out_size, void* d_ws, size_t ws_size,
                              hipStream_t stream) {
    const int N0 = 16384, N1 = 4096, N2 = 1024;
    const int E0 = in_sizes[48] / 2, E1 = in_sizes[49] / 2, E2 = in_sizes[50] / 2;

    const int* idx0 = (const int*)d_in[46];
    const int* idx1 = (const int*)d_in[47];
    const int* ei0  = (const int*)d_in[48];
    const int* ei1  = (const int*)d_in[49];
    const int* ei2  = (const int*)d_in[50];

    float* W = (float*)d_ws;
    size_t off = 0;
    auto alloc = [&](size_t nf) { float* p = W + off; off += (nf + 63) & ~(size_t)63; return p; };
    float* P     = alloc(4194304);   // 16384x256 == 4096x1024
    float* Q     = alloc(4194304);
    float* CAT   = alloc(8486912);   // 16384x518 (also holds 4096x320 for FP2)
    float* xf    = alloc(98304);     // 16384x6
    float* posf  = alloc(49152);     // 16384x3
    float* pos1  = alloc(12288);
    float* pos2  = alloc(3072);
    float* dinv0 = alloc(16384);
    float* dinv1 = alloc(4096);
    float* dinv2 = alloc(1024);
    float* degb  = alloc(16384);
    float* x1    = alloc(262144);    // 4096x64
    float* c2    = alloc(134144);    // 1024x131
    float* xb    = alloc(262144);    // 1024x256
    float* gmaxb = alloc(2048);
    float* rowv  = alloc(1024);
    float* kwb   = alloc(49152);
    int*   kib   = (int*)alloc(49152);
    int*   flg   = (int*)alloc(64);

    auto g1 = [](long n) { return dim3((unsigned)((n + 255) / 256)); };

    auto mm = [&](const float* Ain, int iw, int ib, const float* radd, float* out,
                  int M_, int K_, int N_, long woff, int relu) {
        dim3 g((N_ + 63) / 64, (M_ + 63) / 64);
        k_mm<<<g, 256, 0, stream>>>(Ain, d_in[iw], ib >= 0 ? d_in[ib] : nullptr, radd,
                                    out, M_, K_, N_, woff, relu, flg);
    };
    auto gcn = [&](const float* Ain, int n, int K, int iw, int ib, int C,
                   const int* ei, int E, const float* dinv, float* t, float* out,
                   long woff = 0, const float* radd = nullptr) {
        mm(Ain, iw, -1, radd, t, n, K, C, woff, 0);
        k_self<<<g1((long)n * C), 256, 0, stream>>>(t, dinv, out, n, C);
        k_scatter<<<g1((long)E * C), 256, 0, stream>>>(t, ei, ei + E, dinv, out, E, C);
        k_bias_relu<<<g1((long)n * C), 256, 0, stream>>>(out, d_in[ib], n, C, flg);
    };
    auto mkdinv = [&](const int* ei, int E, int n, float* dinv) {
        k_zero<<<g1(n), 256, 0, stream>>>(degb, n);
        k_deg<<<g1(E), 256, 0, stream>>>(ei + E, degb, E);
        k_dinv<<<g1(n), 256, 0, stream>>>(degb, dinv, n);
    };

    // dtype detection (sa1_w0: 192 elements, scan 192 halves)
    k_detect<<<1, 256, 0, stream>>>((const unsigned short*)d_in[2], in_sizes[2], flg);

    // input conversion & degree norms
    k_cvt_in<<<g1(N0 * 6), 256, 0, stream>>>(d_in[0], xf, N0 * 6, flg);
    k_cvt_in<<<g1(N0 * 3), 256, 0, stream>>>(d_in[1], posf, N0 * 3, flg);
    mkdinv(ei0, E0, N0, dinv0);
    mkdinv(ei1, E1, N1, dinv1);
    mkdinv(ei2, E2, N2, dinv2);

    // SA1: 6->32->32->64 on level-0 graph
    gcn(xf, N0, 6, 2, 3, 32, ei0, E0, dinv0, P, Q);
    gcn(Q, N0, 32, 4, 5, 32, ei0, E0, dinv0, P, Q);
    gcn(Q, N0, 32, 6, 7, 64, ei0, E0, dinv0, P, Q);
    k_gather<<<g1((long)N1 * 64), 256, 0, stream>>>(Q, idx0, x1, N1, 64, 64, 64, 0);
    k_gather<<<g1((long)N1 * 3), 256, 0, stream>>>(posf, idx0, pos1, N1, 3, 3, 3, 0);

    // SA2: [x1|pos1](67) -> 64->64->128 on level-1 graph
    k_copy<<<g1((long)N1 * 64), 256, 0, stream>>>(x1, P, N1, 64, 64, 67, 0);
    k_copy<<<g1((long)N1 * 3), 256, 0, stream>>>(pos1, P, N1, 3, 3, 67, 64);
    gcn(P, N1, 67, 8, 9, 64, ei1, E1, dinv1, Q, P);
    gcn(P, N1, 64, 10, 11, 64, ei1, E1, dinv1, Q, P);
    gcn(P, N1, 64, 12, 13, 128, ei1, E1, dinv1, Q, P);
    k_gather<<<g1((long)N2 * 128), 256, 0, stream>>>(P, idx1, c2, N2, 128, 128, 131, 0);
    k_gather<<<g1((long)N2 * 3), 256, 0, stream>>>(pos1, idx1, pos2, N2, 3, 3, 3, 0);
    k_copy<<<g1((long)N2 * 3), 256, 0, stream>>>(pos2, c2, N2, 3, 3, 131, 128);

    // bottleneck: [x2|pos2](131) -> 128->128->256 on level-2 graph
    gcn(c2, N2, 131, 14, 15, 128, ei2, E2, dinv2, P, Q);
    gcn(Q, N2, 128, 16, 17, 128, ei2, E2, dinv2, P, Q);
    gcn(Q, N2, 128, 18, 19, 256, ei2, E2, dinv2, P, xb);

    // GlobalSA: MLP+BN+relu x2, final linear, column max
    mm(c2, 20, 21, nullptr, P, N2, 131, 512, 0, 0);
    k_bn<<<dim3(512), 256, 0, stream>>>(P, d_in[26], d_in[27], N2, 512, flg);
    mm(P, 22, 23, nullptr, Q, N2, 512, 1024, 0, 0);
    k_bn<<<dim3(1024), 256, 0, stream>>>(Q, d_in[28], d_in[29], N2, 1024, flg);
    mm(Q, 24, 25, nullptr, P, N2, 1024, 2048, 0, 0);
    k_colmax<<<dim3(2048), 256, 0, stream>>>(P, gmaxb, N2, 2048);

    // FP2: interp(gmax-part) == gmax exactly -> rank-1 rowvec; interp xb; concat x1.
    // CAT2 = [interp(xb)(256) | x1(64)] (4096x320); W rows 2048.. are the matching block.
    k_rowvec<<<dim3(4), 256, 0, stream>>>(gmaxb, d_in[30], rowv, flg);
    k_knn_find<<<g1(N1), 256, N2 * 3 * sizeof(float), stream>>>(pos1, pos2, N1, N2, kib, kwb);
    k_knn_apply<<<g1((long)N1 * 256), 256, 0, stream>>>(xb, kib, kwb, CAT, N1, 256, 320);
    k_copy<<<g1((long)N1 * 64), 256, 0, stream>>>(x1, CAT, N1, 64, 64, 320, 256);
    gcn(CAT, N1, 320, 30, 31, 1024, ei1, E1, dinv1, P, Q, 2048L * 1024L, rowv);
    gcn(Q, N1, 1024, 32, 33, 1024, ei1, E1, dinv1, P, Q);
    gcn(Q, N1, 1024, 34, 35, 512, ei1, E1, dinv1, P, Q);   // Q: 4096x512

    // FP1: knn(level1 -> level0) of Q(512), concat raw x -> 518 -> 256->256->128
    k_knn_find<<<g1(N0), 256, N1 * 3 * sizeof(float), stream>>>(posf, pos1, N0, N1, kib, kwb);
    k_knn_apply<<<g1((long)N0 * 512), 256, 0, stream>>>(Q, kib, kwb, CAT, N0, 512, 518);
    k_copy<<<g1((long)N0 * 6), 256, 0, stream>>>(xf, CAT, N0, 6, 6, 518, 512);
    gcn(CAT, N0, 518, 36, 37, 256, ei0, E0, dinv0, P, Q);
    gcn(Q, N0, 256, 38, 39, 256, ei0, E0, dinv0, P, CAT);
    gcn(CAT, N0, 256, 40, 41, 128, ei0, E0, dinv0, P, Q);

    // final MLP: 128 -> 64 (relu) -> 4
    mm(Q, 42, 43, nullptr, P, N0, 128, 64, 0, 1);
    mm(P, 44, 45, nullptr, Q, N0, 64, 4, 0, 0);
    k_out<<<g1(N0 * 4), 256, 0, stream>>>(Q, d_out, N0 * 4, flg);
}

// Round 3
// 1681.649 us; speedup vs baseline: 2.1526x; 2.1526x over previous
//
#include <hip/hip_runtime.h>
#include <hip/hip_bf16.h>

typedef __hip_bfloat16 bf16;

// flag: 1 = float tensors are bf16, 0 = fp32
__device__ __forceinline__ float ldw(const void* p, long i, int isbf) {
    return isbf ? __bfloat162float(((const bf16*)p)[i]) : ((const float*)p)[i];
}

// ---------------------------------------------------------------- dtype detect
__global__ void k_detect(const unsigned short* __restrict__ w, int n, int* __restrict__ flag) {
    __shared__ int cnt;
    if (threadIdx.x == 0) cnt = 0;
    __syncthreads();
    int bad = 0;
    for (int i = threadIdx.x; i < n; i += 256) {
        int e = (w[i] >> 7) & 0xFF;
        if (e == 0xFF || (e != 0 && (e < 64 || e > 190))) bad++;
    }
    atomicAdd(&cnt, bad);
    __syncthreads();
    if (threadIdx.x == 0) *flag = (cnt > n / 16) ? 0 : 1;
}

// ---------------------------------------------------------------- small utils
__global__ void k_cvt_in(const void* __restrict__ s, float* __restrict__ d, int n,
                         const int* __restrict__ flag) {
    int i = blockIdx.x * 256 + threadIdx.x;
    if (i < n) d[i] = ldw(s, i, *flag);
}
__global__ void k_out(const float* __restrict__ s, void* __restrict__ d, int n,
                      const int* __restrict__ flag) {
    int i = blockIdx.x * 256 + threadIdx.x;
    if (i < n) {
        if (*flag) ((bf16*)d)[i] = __float2bfloat16(s[i]);
        else       ((float*)d)[i] = s[i];
    }
}
__global__ void k_zero(float* __restrict__ d, int n) {
    int i = blockIdx.x * 256 + threadIdx.x;
    if (i < n) d[i] = 0.f;
}
__global__ void k_zero_i(int* __restrict__ d, int n) {
    int i = blockIdx.x * 256 + threadIdx.x;
    if (i < n) d[i] = 0;
}

// ---------------------------------------------------------------- CSR build
__global__ void k_count(const int* __restrict__ dst, int* __restrict__ cnt, int E) {
    int i = blockIdx.x * 256 + threadIdx.x;
    if (i < E) atomicAdd(&cnt[dst[i]], 1);
}
__global__ void k_dinv_i(const int* __restrict__ cnt, float* __restrict__ dinv, int n) {
    int i = blockIdx.x * 256 + threadIdx.x;
    if (i < n) dinv[i] = rsqrtf((float)cnt[i] + 1.0f);  // +1 self loop
}
// single block, 1024 threads, exclusive scan of cnt[0..n) -> offs, offs[n]=E
__global__ __launch_bounds__(1024) void k_scan(const int* __restrict__ cnt,
                                               int* __restrict__ offs, int n) {
    __shared__ int sm[1024];
    int t = threadIdx.x;
    int chunk = (n + 1023) >> 10;
    int b0 = t * chunk, b1 = min(b0 + chunk, n);
    int s = 0;
    for (int i = b0; i < b1; i++) s += cnt[i];
    sm[t] = s;
    __syncthreads();
    for (int o = 1; o < 1024; o <<= 1) {
        int v = (t >= o) ? sm[t - o] : 0;
        __syncthreads();
        sm[t] += v;
        __syncthreads();
    }
    int run = sm[t] - s;  // exclusive
    for (int i = b0; i < b1; i++) { offs[i] = run; run += cnt[i]; }
    if (t == 1023) offs[n] = sm[1023];
}
__global__ void k_fill(const int* __restrict__ src, const int* __restrict__ dst,
                       const int* __restrict__ offs, int* __restrict__ cur,
                       int* __restrict__ bkt, int E) {
    int e = blockIdx.x * 256 + threadIdx.x;
    if (e < E) {
        int d = dst[e];
        int p = atomicAdd(&cur[d], 1);
        bkt[offs[d] + p] = src[e];
    }
}

// ---------------------------------------------------------------- matmul
// C(MxN) = A(MxK,f32) @ W(KxN, flagged dtype, offset woff)
// epilogue: v = acc * (rs?rs[r]:1) + bias[c] + radd[c]*(rsc?rsc[r]:1); relu opt.
// M % 64 == 0 assumed. 64x64 tile, 256 threads, 4x4 contiguous per thread.
__global__ __launch_bounds__(256) void k_mm(
    const float* __restrict__ A, const void* __restrict__ Wt,
    const void* __restrict__ bias, const float* __restrict__ radd,
    const float* __restrict__ rsc, const float* __restrict__ rs,
    float* __restrict__ C, int M, int K, int N, long woff, int relu,
    const int* __restrict__ flag)
{
    __shared__ float As[16][64];
    __shared__ float Bs[16][64];
    const int isbf = *flag;
    const int tid = threadIdx.x;
    const int tx = tid & 15, ty = tid >> 4;
    const int bx = blockIdx.x, by = blockIdx.y;
    float acc[4][4] = {};
    // staging maps (float4 LDS writes)
    const int akk = tid >> 4, am4 = (tid & 15) << 2;  // A: 4 rows, 1 k
    const int bkk = tid >> 4, bn4 = (tid & 15) << 2;  // B: 1 k, 4 cols
    for (int k0 = 0; k0 < K; k0 += 16) {
        {
            int kg = k0 + akk;
            float4 v = {0.f, 0.f, 0.f, 0.f};
            if (kg < K) {
                long base = (long)(by * 64 + am4) * K + kg;
                v.x = A[base]; v.y = A[base + K]; v.z = A[base + 2 * K]; v.w = A[base + 3 * K];
            }
            *(float4*)&As[akk][am4] = v;
        }
        {
            int kg = k0 + bkk;
            float4 v = {0.f, 0.f, 0.f, 0.f};
            if (kg < K) {
                long base = woff + (long)kg * N + bx * 64 + bn4;
                int c0 = bx * 64 + bn4;
                if (c0 + 3 < N) {
                    v.x = ldw(Wt, base, isbf); v.y = ldw(Wt, base + 1, isbf);
                    v.z = ldw(Wt, base + 2, isbf); v.w = ldw(Wt, base + 3, isbf);
                } else {
                    if (c0 < N) v.x = ldw(Wt, base, isbf);
                    if (c0 + 1 < N) v.y = ldw(Wt, base + 1, isbf);
                    if (c0 + 2 < N) v.z = ldw(Wt, base + 2, isbf);
                }
            }
            *(float4*)&Bs[bkk][bn4] = v;
        }
        __syncthreads();
        #pragma unroll
        for (int kk = 0; kk < 16; kk++) {
            float4 a = *(const float4*)&As[kk][ty << 2];
            float4 b = *(const float4*)&Bs[kk][tx << 2];
            float av[4] = {a.x, a.y, a.z, a.w};
            float bv[4] = {b.x, b.y, b.z, b.w};
            #pragma unroll
            for (int i = 0; i < 4; i++)
                #pragma unroll
                for (int j = 0; j < 4; j++)
                    acc[i][j] = fmaf(av[i], bv[j], acc[i][j]);
        }
        __syncthreads();
    }
    const int col = bx * 64 + (tx << 2);
    #pragma unroll
    for (int i = 0; i < 4; i++) {
        int r = by * 64 + (ty << 2) + i;
        float m = rs ? rs[r] : 1.0f;
        float rr = rsc ? rsc[r] : 1.0f;
        float v[4];
        #pragma unroll
        for (int j = 0; j < 4; j++) {
            v[j] = acc[i][j] * m;
            int c = col + j;
            if (c < N) {
                if (bias) v[j] += ldw(bias, c, isbf);
                if (radd) v[j] += radd[c] * rr;
            }
            if (relu) v[j] = fmaxf(v[j], 0.f);
        }
        if (col + 3 < N) {
            float4 o = {v[0], v[1], v[2], v[3]};
            *(float4*)&C[(long)r * N + col] = o;
        } else {
            for (int j = 0; j < 4; j++)
                if (col + j < N) C[(long)r * N + col + j] = v[j];
        }
    }
}

// ---------------------------------------------------------------- CSR aggregation
// out[d] = relu( dinv[d]*(t[d] + sum_{s in adj(d)} t[s]) + bias ), t prescaled by dinv
__global__ __launch_bounds__(256) void k_aggr(const float* __restrict__ t,
    const int* __restrict__ offs, const int* __restrict__ bkt,
    const float* __restrict__ dinv, const void* __restrict__ bias,
    float* __restrict__ out, int n, int C, int relu, const int* __restrict__ flag)
{
    const int G = C >> 2;
    long i = blockIdx.x * 256L + threadIdx.x;
    if (i >= (long)n * G) return;
    int d = (int)(i / G), g = (int)(i % G);
    const float4* t4 = (const float4*)t;
    float4 acc = t4[(long)d * G + g];
    int o0 = offs[d], o1 = offs[d + 1];
    for (int j = o0; j < o1; j++) {
        int s = bkt[j];
        float4 v = t4[(long)s * G + g];
        acc.x += v.x; acc.y += v.y; acc.z += v.z; acc.w += v.w;
    }
    float dd = dinv[d];
    acc.x *= dd; acc.y *= dd; acc.z *= dd; acc.w *= dd;
    if (bias) {
        int isbf = *flag; int c = g << 2;
        acc.x += ldw(bias, c, isbf); acc.y += ldw(bias, c + 1, isbf);
        acc.z += ldw(bias, c + 2, isbf); acc.w += ldw(bias, c + 3, isbf);
    }
    if (relu) {
        acc.x = fmaxf(acc.x, 0.f); acc.y = fmaxf(acc.y, 0.f);
        acc.z = fmaxf(acc.z, 0.f); acc.w = fmaxf(acc.w, 0.f);
    }
    ((float4*)out)[(long)d * G + g] = acc;
}

__global__ void k_rowmul(float* __restrict__ h, const float* __restrict__ s, int n, int C) {
    long i = blockIdx.x * 256L + threadIdx.x;
    if (i < (long)n * C) h[i] *= s[i / C];
}
// sigma = Ahat @ 1
__global__ void k_sigacc(const int* __restrict__ src, const int* __restrict__ dst,
                         const float* __restrict__ dinv, float* __restrict__ sig, int E) {
    int e = blockIdx.x * 256 + threadIdx.x;
    if (e < E) atomicAdd(&sig[dst[e]], dinv[src[e]]);
}
__global__ void k_sigfin(float* __restrict__ sig, const float* __restrict__ dinv, int n) {
    int i = blockIdx.x * 256 + threadIdx.x;
    if (i < n) sig[i] = dinv[i] * (sig[i] + dinv[i]);
}
// rowv[n] += sum_{c in block} gmax[c]*W[c,n]  (W 2048x1024)
__global__ void k_rowvec_acc(const float* __restrict__ gmax, const void* __restrict__ W,
                             float* __restrict__ out, const int* __restrict__ flag) {
    int n = blockIdx.x * 256 + threadIdx.x;
    if (n >= 1024) return;
    const int isbf = *flag;
    int c0 = blockIdx.y * 128;
    float s = 0.f;
    for (int c = c0; c < c0 + 128; c++) s += gmax[c] * ldw(W, (long)c * 1024 + n, isbf);
    atomicAdd(&out[n], s);
}

// ---------------------------------------------------------------- batchnorm + relu (n<=1024)
__global__ __launch_bounds__(256) void k_bn(float* __restrict__ h, const void* __restrict__ gamma,
                                            const void* __restrict__ beta, int n, int C,
                                            const int* __restrict__ flag) {
    int c = blockIdx.x;
    int tid = threadIdx.x;
    __shared__ float sm[256];
    float v[4];
    float s = 0.f;
    #pragma unroll
    for (int u = 0; u < 4; u++) {
        int r = tid + u * 256;
        v[u] = (r < n) ? h[(long)r * C + c] : 0.f;
        s += v[u];
    }
    sm[tid] = s; __syncthreads();
    for (int o = 128; o > 0; o >>= 1) { if (tid < o) sm[tid] += sm[tid + o]; __syncthreads(); }
    float mu = sm[0] / n;
    __syncthreads();
    float s2 = 0.f;
    #pragma unroll
    for (int u = 0; u < 4; u++) {
        int r = tid + u * 256;
        if (r < n) { float d = v[u] - mu; s2 += d * d; }
    }
    sm[tid] = s2; __syncthreads();
    for (int o = 128; o > 0; o >>= 1) { if (tid < o) sm[tid] += sm[tid + o]; __syncthreads(); }
    float var = sm[0] / n;
    float rsq = rsqrtf(var + 1e-5f);
    float g = ldw(gamma, c, *flag), be = ldw(beta, c, *flag);
    #pragma unroll
    for (int u = 0; u < 4; u++) {
        int r = tid + u * 256;
        if (r < n) h[(long)r * C + c] = fmaxf((v[u] - mu) * rsq * g + be, 0.f);
    }
}

// column max of h(1024 x 2048): 32 blocks x 64 cols
__global__ __launch_bounds__(256) void k_cmax(const float* __restrict__ h, float* __restrict__ out) {
    __shared__ float sm[256];
    int coff = threadIdx.x & 63, rq = threadIdx.x >> 6;
    int c = blockIdx.x * 64 + coff;
    float m = -3.0e38f;
    for (int r = rq; r < 1024; r += 4) m = fmaxf(m, h[(long)r * 2048 + c]);
    sm[threadIdx.x] = m;
    __syncthreads();
    if (rq == 0) {
        m = fmaxf(fmaxf(sm[coff], sm[64 + coff]), fmaxf(sm[128 + coff], sm[192 + coff]));
        out[c] = m;
    }
}

// ---------------------------------------------------------------- gather / strided copy
__global__ void k_gather(const float* __restrict__ src, const int* __restrict__ idx,
                         float* __restrict__ dst, int n, int ncol, int ss, int ds, int doff) {
    long i = blockIdx.x * 256L + threadIdx.x;
    if (i < (long)n * ncol) {
        int r = (int)(i / ncol), c = (int)(i % ncol);
        dst[(long)r * ds + doff + c] = src[(long)idx[r] * ss + c];
    }
}
__global__ void k_copy(const float* __restrict__ src, float* __restrict__ dst,
                       int n, int ncol, int ss, int ds, int doff) {
    long i = blockIdx.x * 256L + threadIdx.x;
    if (i < (long)n * ncol) {
        int r = (int)(i / ncol), c = (int)(i % ncol);
        dst[(long)r * ds + doff + c] = src[(long)r * ss + c];
    }
}

// ---------------------------------------------------------------- kNN (k=3), one wave per dst
__device__ __forceinline__ bool knn_better(float d, int i, float D, int I) {
    return d < D || (d == D && i < I);
}
__global__ __launch_bounds__(256) void k_knn_w(const float* __restrict__ pdst,
                                               const float* __restrict__ psrc,
                                               int M, int Ns,
                                               int* __restrict__ kidx, float* __restrict__ kw) {
    int wid = (blockIdx.x * 256 + threadIdx.x) >> 6;
    int lane = threadIdx.x & 63;
    if (wid >= M) return;
    float x = pdst[wid * 3], y = pdst[wid * 3 + 1], z = pdst[wid * 3 + 2];
    float nd = x * x + y * y + z * z;
    float bd0 = 3.4e38f, bd1 = 3.4e38f, bd2 = 3.4e38f;
    int bi0 = 0x7fffffff, bi1 = 0x7fffffff, bi2 = 0x7fffffff;
    for (int s = lane; s < Ns; s += 64) {
        float sx = psrc[3 * s], sy = psrc[3 * s + 1], sz = psrc[3 * s + 2];
        float ns = sx * sx + sy * sy + sz * sz;
        float d2 = nd + ns - 2.0f * (x * sx + y * sy + z * sz);
        if (d2 < bd2) {
            if (d2 < bd0)      { bd2 = bd1; bi2 = bi1; bd1 = bd0; bi1 = bi0; bd0 = d2; bi0 = s; }
            else if (d2 < bd1) { bd2 = bd1; bi2 = bi1; bd1 = d2; bi1 = s; }
            else               { bd2 = d2; bi2 = s; }
        }
    }
    #pragma unroll
    for (int off = 32; off >= 1; off >>= 1) {
        float od0 = __shfl_xor(bd0, off, 64); int oi0 = __shfl_xor(bi0, off, 64);
        float od1 = __shfl_xor(bd1, off, 64); int oi1 = __shfl_xor(bi1, off, 64);
        float od2 = __shfl_xor(bd2, off, 64); int oi2 = __shfl_xor(bi2, off, 64);
        float dq[3] = {od0, od1, od2}; int iq[3] = {oi0, oi1, oi2};
        #pragma unroll
        for (int q = 0; q < 3; q++) {
            float dd = dq[q]; int ii = iq[q];
            if (knn_better(dd, ii, bd0, bi0))      { bd2 = bd1; bi2 = bi1; bd1 = bd0; bi1 = bi0; bd0 = dd; bi0 = ii; }
            else if (knn_better(dd, ii, bd1, bi1)) { bd2 = bd1; bi2 = bi1; bd1 = dd; bi1 = ii; }
            else if (knn_better(dd, ii, bd2, bi2)) { bd2 = dd; bi2 = ii; }
        }
    }
    if (lane == 0) {
        kidx[wid * 3] = bi0; kidx[wid * 3 + 1] = bi1; kidx[wid * 3 + 2] = bi2;
        kw[wid * 3]     = 1.0f / fmaxf(bd0, 1e-16f);
        kw[wid * 3 + 1] = 1.0f / fmaxf(bd1, 1e-16f);
        kw[wid * 3 + 2] = 1.0f / fmaxf(bd2, 1e-16f);
    }
}

__global__ void k_knn_apply4(const float* __restrict__ h, const int* __restrict__ kidx,
                             const float* __restrict__ kw, float* __restrict__ out,
                             int M, int C, int ds) {  // C%4==0, ds%4==0
    const int G = C >> 2;
    long i = blockIdx.x * 256L + threadIdx.x;
    if (i >= (long)M * G) return;
    int r = (int)(i / G), g = (int)(i % G);
    int i0 = kidx[r * 3], i1 = kidx[r * 3 + 1], i2 = kidx[r * 3 + 2];
    float w0 = kw[r * 3], w1 = kw[r * 3 + 1], w2 = kw[r * 3 + 2];
    float inv = 1.0f / (w0 + w1 + w2);
    const float4* h4 = (const float4*)h;
    float4 a = h4[(long)i0 * G + g], b = h4[(long)i1 * G + g], c = h4[(long)i2 * G + g];
    float4 o;
    o.x = (w0 * a.x + w1 * b.x + w2 * c.x) * inv;
    o.y = (w0 * a.y + w1 * b.y + w2 * c.y) * inv;
    o.z = (w0 * a.z + w1 * b.z + w2 * c.z) * inv;
    o.w = (w0 * a.w + w1 * b.w + w2 * c.w) * inv;
    *(float4*)&out[(long)r * ds + (g << 2)] = o;
}
__global__ void k_knn_apply2(const float* __restrict__ h, const int* __restrict__ kidx,
                             const float* __restrict__ kw, float* __restrict__ out,
                             int M, int C, int ds) {  // C%2==0, ds%2==0
    const int G = C >> 1;
    long i = blockIdx.x * 256L + threadIdx.x;
    if (i >= (long)M * G) return;
    int r = (int)(i / G), g = (int)(i % G);
    int i0 = kidx[r * 3], i1 = kidx[r * 3 + 1], i2 = kidx[r * 3 + 2];
    float w0 = kw[r * 3], w1 = kw[r * 3 + 1], w2 = kw[r * 3 + 2];
    float inv = 1.0f / (w0 + w1 + w2);
    const float2* h2 = (const float2*)h;
    float2 a = h2[(long)i0 * G + g], b = h2[(long)i1 * G + g], c = h2[(long)i2 * G + g];
    float2 o;
    o.x = (w0 * a.x + w1 * b.x + w2 * c.x) * inv;
    o.y = (w0 * a.y + w1 * b.y + w2 * c.y) * inv;
    *(float2*)&out[(long)r * ds + (g << 1)] = o;
}

// ---------------------------------------------------------------- launch
extern "C" void kernel_launch(void* const* d_in, const int* in_sizes, int n_in,
                              void* d_out, int out_size, void* d_ws, size_t ws_size,
                              hipStream_t stream) {
    const int N0 = 16384, N1 = 4096, N2 = 1024;
    const int E0 = in_sizes[48] / 2, E1 = in_sizes[49] / 2, E2 = in_sizes[50] / 2;

    const int* idx0 = (const int*)d_in[46];
    const int* idx1 = (const int*)d_in[47];
    const int* ei0  = (const int*)d_in[48];
    const int* ei1  = (const int*)d_in[49];
    const int* ei2  = (const int*)d_in[50];

    float* W = (float*)d_ws;
    size_t off = 0;
    auto alloc = [&](size_t nf) { float* p = W + off; off += (nf + 63) & ~(size_t)63; return p; };
    float* P     = alloc(4194304);   // 16384x256 == 4096x1024 == 1024x2048(+)
    float* Q     = alloc(4194304);
    float* CAT   = alloc(8486912);   // 16384x518 >= 16384x256 >= 4096x320
    float* xf    = alloc(98304);     // 16384x6 (also final 16384x4 out)
    float* posf  = alloc(49152);
    float* pos1  = alloc(12288);
    float* pos2  = alloc(3072);
    float* dinv0 = alloc(16384);
    float* dinv1 = alloc(4096);
    float* dinv2 = alloc(1024);
    float* x1    = alloc(262144);    // 4096x64
    float* c2    = alloc(134144);    // 1024x131
    float* xb    = alloc(262144);    // 1024x256
    float* gmaxb = alloc(2048);
    float* rowv  = alloc(1024);
    float* sigb  = alloc(4096);
    float* kwb   = alloc(49152);
    int*   kib   = (int*)alloc(49152);
    int*   flg   = (int*)alloc(64);
    int*   cntb  = (int*)alloc(16384);
    int*   offs0 = (int*)alloc(16448);
    int*   offs1 = (int*)alloc(4160);
    int*   offs2 = (int*)alloc(1088);
    int*   bkt0  = (int*)alloc(E0);
    int*   bkt1  = (int*)alloc(E1);
    int*   bkt2  = (int*)alloc(E2);

    auto g1 = [](long n) { return dim3((unsigned)((n + 255) / 256)); };

    auto mm = [&](const float* Ain, int iw, int ib, const float* radd, const float* rsc,
                  const float* rs, float* out, int M_, int K_, int N_, long woff, int relu) {
        dim3 g((N_ + 63) / 64, M_ / 64);
        k_mm<<<g, 256, 0, stream>>>(Ain, d_in[iw], ib >= 0 ? d_in[ib] : nullptr,
                                    radd, rsc, rs, out, M_, K_, N_, woff, relu, flg);
    };
    auto gcn = [&](const float* Ain, int n, int K, int iw, int ib, int C,
                   const int* offs, const int* bkt, const float* dinv, float* t, float* out) {
        mm(Ain, iw, -1, nullptr, nullptr, dinv, t, n, K, C, 0, 0);   // t' = dinv * (A@W)
        k_aggr<<<g1((long)n * (C >> 2)), 256, 0, stream>>>(t, offs, bkt, dinv, d_in[ib],
                                                           out, n, C, 1, flg);
    };
    auto csr = [&](const int* ei, int E, int n, int* offs, int* bkt, float* dinv) {
        k_zero_i<<<g1(n), 256, 0, stream>>>(cntb, n);
        k_count<<<g1(E), 256, 0, stream>>>(ei + E, cntb, E);
        k_dinv_i<<<g1(n), 256, 0, stream>>>(cntb, dinv, n);
        k_scan<<<1, 1024, 0, stream>>>(cntb, offs, n);
        k_zero_i<<<g1(n), 256, 0, stream>>>(cntb, n);
        k_fill<<<g1(E), 256, 0, stream>>>(ei, ei + E, offs, cntb, bkt, E);
    };

    // dtype detection + input conversion + CSR
    k_detect<<<1, 256, 0, stream>>>((const unsigned short*)d_in[2], in_sizes[2], flg);
    k_cvt_in<<<g1(N0 * 6), 256, 0, stream>>>(d_in[0], xf, N0 * 6, flg);
    k_cvt_in<<<g1(N0 * 3), 256, 0, stream>>>(d_in[1], posf, N0 * 3, flg);
    csr(ei0, E0, N0, offs0, bkt0, dinv0);
    csr(ei1, E1, N1, offs1, bkt1, dinv1);
    csr(ei2, E2, N2, offs2, bkt2, dinv2);

    // SA1: 6->32->32->64 on level-0 graph
    gcn(xf, N0, 6, 2, 3, 32, offs0, bkt0, dinv0, P, Q);
    gcn(Q, N0, 32, 4, 5, 32, offs0, bkt0, dinv0, P, Q);
    gcn(Q, N0, 32, 6, 7, 64, offs0, bkt0, dinv0, P, Q);
    k_gather<<<g1((long)N1 * 64), 256, 0, stream>>>(Q, idx0, x1, N1, 64, 64, 64, 0);
    k_gather<<<g1((long)N1 * 3), 256, 0, stream>>>(posf, idx0, pos1, N1, 3, 3, 3, 0);

    // SA2: [x1|pos1](67) -> 64->64->128 on level-1 graph
    k_copy<<<g1((long)N1 * 64), 256, 0, stream>>>(x1, P, N1, 64, 64, 67, 0);
    k_copy<<<g1((long)N1 * 3), 256, 0, stream>>>(pos1, P, N1, 3, 3, 67, 64);
    gcn(P, N1, 67, 8, 9, 64, offs1, bkt1, dinv1, Q, P);
    gcn(P, N1, 64, 10, 11, 64, offs1, bkt1, dinv1, Q, P);
    gcn(P, N1, 64, 12, 13, 128, offs1, bkt1, dinv1, Q, P);
    k_gather<<<g1((long)N2 * 128), 256, 0, stream>>>(P, idx1, c2, N2, 128, 128, 131, 0);
    k_gather<<<g1((long)N2 * 3), 256, 0, stream>>>(pos1, idx1, pos2, N2, 3, 3, 3, 0);
    k_copy<<<g1((long)N2 * 3), 256, 0, stream>>>(pos2, c2, N2, 3, 3, 131, 128);

    // bottleneck: 131 -> 128->128->256 on level-2 graph
    gcn(c2, N2, 131, 14, 15, 128, offs2, bkt2, dinv2, P, Q);
    gcn(Q, N2, 128, 16, 17, 128, offs2, bkt2, dinv2, P, Q);
    gcn(Q, N2, 128, 18, 19, 256, offs2, bkt2, dinv2, P, xb);

    // GlobalSA
    mm(c2, 20, 21, nullptr, nullptr, nullptr, P, N2, 131, 512, 0, 0);
    k_bn<<<dim3(512), 256, 0, stream>>>(P, d_in[26], d_in[27], N2, 512, flg);
    mm(P, 22, 23, nullptr, nullptr, nullptr, Q, N2, 512, 1024, 0, 0);
    k_bn<<<dim3(1024), 256, 0, stream>>>(Q, d_in[28], d_in[29], N2, 1024, flg);
    mm(Q, 24, 25, nullptr, nullptr, nullptr, P, N2, 1024, 2048, 0, 0);
    k_cmax<<<dim3(32), 256, 0, stream>>>(P, gmaxb);

    // FP2: out1 = relu( (Ahat [interp(xb)|x1]) @ W[2048:] + sigma*rowv + b )
    k_zero<<<g1(1024), 256, 0, stream>>>(rowv, 1024);
    k_rowvec_acc<<<dim3(4, 16), 256, 0, stream>>>(gmaxb, d_in[30], rowv, flg);
    k_knn_w<<<g1((long)N1 * 64), 256, 0, stream>>>(pos1, pos2, N1, N2, kib, kwb);
    k_knn_apply4<<<g1((long)N1 * 64), 256, 0, stream>>>(xb, kib, kwb, CAT, N1, 256, 320);
    k_copy<<<g1((long)N1 * 64), 256, 0, stream>>>(x1, CAT, N1, 64, 64, 320, 256);
    k_rowmul<<<g1((long)N1 * 320), 256, 0, stream>>>(CAT, dinv1, N1, 320);
    k_aggr<<<g1((long)N1 * 80), 256, 0, stream>>>(CAT, offs1, bkt1, dinv1, nullptr,
                                                  P, N1, 320, 0, flg);
    k_zero<<<g1(N1), 256, 0, stream>>>(sigb, N1);
    k_sigacc<<<g1(E1), 256, 0, stream>>>(ei1, ei1 + E1, dinv1, sigb, E1);
    k_sigfin<<<g1(N1), 256, 0, stream>>>(sigb, dinv1, N1);
    mm(P, 30, 31, rowv, sigb, nullptr, Q, N1, 320, 1024, 2048L * 1024L, 1);
    gcn(Q, N1, 1024, 32, 33, 1024, offs1, bkt1, dinv1, P, Q);
    gcn(Q, N1, 1024, 34, 35, 512, offs1, bkt1, dinv1, P, Q);   // Q: 4096x512

    // FP1
    k_knn_w<<<g1((long)N0 * 64), 256, 0, stream>>>(posf, pos1, N0, N1, kib, kwb);
    k_knn_apply2<<<g1((long)N0 * 256), 256, 0, stream>>>(Q, kib, kwb, CAT, N0, 512, 518);
    k_copy<<<g1((long)N0 * 6), 256, 0, stream>>>(xf, CAT, N0, 6, 6, 518, 512);
    gcn(CAT, N0, 518, 36, 37, 256, offs0, bkt0, dinv0, P, Q);
    gcn(Q, N0, 256, 38, 39, 256, offs0, bkt0, dinv0, P, CAT);
    gcn(CAT, N0, 256, 40, 41, 128, offs0, bkt0, dinv0, P, Q);

    // final MLP: 128 -> 64 (relu) -> 4
    mm(Q, 42, 43, nullptr, nullptr, nullptr, P, N0, 128, 64, 0, 1);
    mm(P, 44, 45, nullptr, nullptr, nullptr, xf, N0, 64, 4, 0, 0);
    k_out<<<g1(N0 * 4), 256, 0, stream>>>(xf, d_out, N0 * 4, flg);
}